// Round 15
// baseline (177.706 us; speedup 1.0000x reference)
//
#include <hip/hip_runtime.h>
#include <hip/hip_bf16.h>

typedef float f32x4 __attribute__((ext_vector_type(4)));
typedef float f32x16 __attribute__((ext_vector_type(16)));
typedef _Float16 half8 __attribute__((ext_vector_type(8)));
typedef __bf16 bf16x8 __attribute__((ext_vector_type(8)));
typedef __bf16 bf16x4 __attribute__((ext_vector_type(4)));
typedef unsigned short ushort_t;

constexpr int Bb = 16, Ss = 4096, Dd = 64;
constexpr int KBLK = 32, QBLK = 128;
constexpr int NT = Ss / KBLK;   // 128
constexpr int KD = KBLK * Dd;   // elements per K tile
constexpr float kLOG2E = 1.44269504088896340736f;
constexpr float DEFER_THR = 10.0f;   // exp2(10)=1024 max P; fp16-safe

constexpr int KP_BLOCKS = (Bb * Ss * Dd / 8) / 256;      // 2048
constexpr int VT_BLOCKS = (Bb * Dd * (Ss / 32)) / 256;   // 512

#define GLOAD_LDS16(gp, lp)                                                              \
    __builtin_amdgcn_global_load_lds(                                                    \
        (const __attribute__((address_space(1))) void*)(gp),                             \
        (__attribute__((address_space(3))) void*)(lp), 16, 0, 0)

// ------- pre-pass: K -> f16 hi/lo [b][s][d]; V -> Vt f16 [b][d][s] (round-6 verified) -
__global__ __launch_bounds__(256)
void prep_f16s(const float* __restrict__ K, const float* __restrict__ V,
               _Float16* __restrict__ Khi, _Float16* __restrict__ Klo,
               _Float16* __restrict__ Vt)
{
    const int bid = blockIdx.x;
    if (bid < KP_BLOCKS) {
        const size_t idx = ((size_t)bid * 256 + threadIdx.x) * 8;
        const float4 a = *reinterpret_cast<const float4*>(K + idx);
        const float4 c = *reinterpret_cast<const float4*>(K + idx + 4);
        float xs[8] = {a.x, a.y, a.z, a.w, c.x, c.y, c.z, c.w};
        half8 h8, l8;
#pragma unroll
        for (int i = 0; i < 8; ++i) {
            const _Float16 h = (_Float16)xs[i];
            h8[i] = h;
            l8[i] = (_Float16)(xs[i] - (float)h);
        }
        *reinterpret_cast<half8*>(Khi + idx) = h8;
        *reinterpret_cast<half8*>(Klo + idx) = l8;
    } else {
        const int t = (bid - KP_BLOCKS) * 256 + threadIdx.x;
        const int d = t & 63;
        const int s32 = (t >> 6) & (Ss / 32 - 1);
        const int b = t >> 13;
        const float* vp = V + ((size_t)b * Ss + (size_t)s32 * 32) * Dd + d;
        __align__(16) _Float16 ob[32];
#pragma unroll
        for (int j = 0; j < 32; ++j) ob[j] = (_Float16)vp[(size_t)j * Dd];
        _Float16* op = Vt + ((size_t)b * Dd + d) * Ss + (size_t)s32 * 32;
#pragma unroll
        for (int j8 = 0; j8 < 4; ++j8)
            *reinterpret_cast<half8*>(op + j8 * 8) = *reinterpret_cast<half8*>(ob + j8 * 8);
    }
}

union H8 { half8 h; unsigned int u[4]; };

// ------- main v15: v14 (160us best) + VALU trim --------------------------------------
// Changes vs v14 (numerics byte-identical):
//  1. hoisted zero-acc: first QK MFMA takes ZACC as C (no per-tile S zeroing)
//  2. v_max3 tree for tile-max (15 -> 8 instr)
//  3. unroll-by-2 main loop: LDS slots compile-time const, staging via running ptrs
//  4. launch_bounds (512,3): VGPR headroom (grid-limited at 2 blocks/CU anyway)
__global__ __launch_bounds__(512, 3)
void attn_fwd_v15(const float* __restrict__ Q, const float* __restrict__ inv_scale,
                  const _Float16* __restrict__ Khi, const _Float16* __restrict__ Klo,
                  const _Float16* __restrict__ Vt, float* __restrict__ Out)
{
    __shared__ __align__(16) unsigned char smem[48 * 1024];

    const int tid = threadIdx.x;
    const int lane = tid & 63;
    const int w = tid >> 6;
    const int p = w & 1;
    const int qg = w >> 1;          // 0..3
    const int l31 = lane & 31;
    const int hi = lane >> 5;

    // T1 XCD swizzle: 512 blocks -> each XCD owns 64 consecutive (2 batches)
    const int bid = (blockIdx.x & 7) * 64 + (blockIdx.x >> 3);
    const int b = bid >> 5;
    const int q0 = (bid & 31) * QBLK;

    const _Float16* KhB = Khi + (size_t)b * Ss * Dd;
    const _Float16* KlB = Klo + (size_t)b * Ss * Dd;
    const _Float16* VB = Vt + (size_t)b * Dd * Ss;

    // staging: linear LDS dest, swizzle pre-applied on the GLOBAL source (rule #21).
    // waves 0-3 stage Khi+Klo, waves 4-7 stage Vt.
    const int c = tid & 255;
    const int kk = c >> 3;
    const int ksrc = kk * Dd + (((c & 7) ^ (kk & 7)) << 3);
    const int dd_ = c >> 2;
    const size_t vsrc = (size_t)dd_ * Ss + (((c & 3) ^ ((dd_ >> 1) & 3)) << 3);

    // prologue: tiles 0,1 -> slots 0,1
    if (tid < 256) {
        GLOAD_LDS16(KhB + ksrc, smem + c * 16);
        GLOAD_LDS16(KhB + ksrc + KD, smem + 4096 + c * 16);
        GLOAD_LDS16(KlB + ksrc, smem + 16384 + c * 16);
        GLOAD_LDS16(KlB + ksrc + KD, smem + 16384 + 4096 + c * 16);
    } else {
        GLOAD_LDS16(VB + vsrc, smem + 32768 + c * 16);
        GLOAD_LDS16(VB + vsrc + KBLK, smem + 32768 + 4096 + c * 16);
    }

    // running staging pointers (start at tile 2)
    const _Float16* khp = KhB + ksrc + 2 * KD;
    const _Float16* klp = KlB + ksrc + 2 * KD;
    const _Float16* vpp = VB + vsrc + 2 * KBLK;

    // LDS read byte-offsets (swizzled), constant per thread
    int koff[4], voff[4];
#pragma unroll
    for (int ks = 0; ks < 4; ++ks)
        koff[ks] = l31 * 128 + ((((ks << 1) + hi) ^ (l31 & 7)) << 4);
#pragma unroll
    for (int i = 0; i < 4; ++i) {   // i = dblk*2 + ks ; conflict-free V swizzle
        const int d = (i >> 1) * 32 + l31;
        voff[i] = d * 64 + (((((i & 1) << 1) + hi) ^ ((d >> 1) & 3)) << 4);
    }

    // Q fragments f16 hi/lo, scale*log2e folded; lane: col q = l31, d = ks*16 + hi*8 ..+8
    H8 qhi[4], qlo[4];
    {
        const float s2 = (1.0f / inv_scale[0]) * kLOG2E;
        const float* qrow = Q + ((size_t)b * Ss + q0 + qg * 32 + l31) * Dd;
#pragma unroll
        for (int ks = 0; ks < 4; ++ks) {
            const int d0 = ks * 16 + hi * 8;
            const float4 a = *reinterpret_cast<const float4*>(qrow + d0);
            const float4 cc = *reinterpret_cast<const float4*>(qrow + d0 + 4);
            float xs[8] = {a.x, a.y, a.z, a.w, cc.x, cc.y, cc.z, cc.w};
#pragma unroll
            for (int i = 0; i < 8; ++i) {
                const float x = xs[i] * s2;
                const _Float16 h = (_Float16)x;
                qhi[ks].h[i] = h;
                qlo[ks].h[i] = (_Float16)(x - (float)h);
            }
        }
    }

    f32x16 O0, O1, ZACC;
#pragma unroll
    for (int r = 0; r < 16; ++r) { O0[r] = 0.f; O1[r] = 0.f; ZACC[r] = 0.f; }
    float m_run = -INFINITY, l_run = 0.f;

    __syncthreads();   // tiles 0,1 resident (barrier drains vmcnt)

    // per-tile compute: QK (slots via SL), softmax, pack, PV. Numerics == v14.
#define PROCESS(SL)                                                                        \
    do {                                                                                   \
        const unsigned char* khbase = smem + (SL) * 4096;                                  \
        const unsigned char* klbase = smem + 16384 + (SL) * 4096;                          \
        const unsigned char* vbase = smem + 32768 + (SL) * 4096;                           \
        const half8 kh0 = *reinterpret_cast<const half8*>(khbase + koff[0]);               \
        const half8 kl0 = *reinterpret_cast<const half8*>(klbase + koff[0]);               \
        f32x16 S = __builtin_amdgcn_mfma_f32_32x32x16_f16(kh0, qhi[0].h, ZACC, 0, 0, 0);   \
        S = __builtin_amdgcn_mfma_f32_32x32x16_f16(kl0, qhi[0].h, S, 0, 0, 0);             \
        S = __builtin_amdgcn_mfma_f32_32x32x16_f16(kh0, qlo[0].h, S, 0, 0, 0);             \
        _Pragma("unroll") for (int ks = 1; ks < 4; ++ks) {                                 \
            const half8 kh = *reinterpret_cast<const half8*>(khbase + koff[ks]);           \
            const half8 kl = *reinterpret_cast<const half8*>(klbase + koff[ks]);           \
            S = __builtin_amdgcn_mfma_f32_32x32x16_f16(kh, qhi[ks].h, S, 0, 0, 0);         \
            S = __builtin_amdgcn_mfma_f32_32x32x16_f16(kl, qhi[ks].h, S, 0, 0, 0);         \
            S = __builtin_amdgcn_mfma_f32_32x32x16_f16(kh, qlo[ks].h, S, 0, 0, 0);         \
        }                                                                                  \
        /* max3 tree (v_max3_f32 fusion) */                                                \
        const float a0 = fmaxf(fmaxf(S[0], S[1]), S[2]);                                   \
        const float a1 = fmaxf(fmaxf(S[3], S[4]), S[5]);                                   \
        const float a2 = fmaxf(fmaxf(S[6], S[7]), S[8]);                                   \
        const float a3 = fmaxf(fmaxf(S[9], S[10]), S[11]);                                 \
        const float a4 = fmaxf(fmaxf(S[12], S[13]), S[14]);                                \
        const float b0 = fmaxf(fmaxf(a0, a1), a2);                                         \
        const float b1 = fmaxf(fmaxf(a3, a4), S[15]);                                      \
        float tmax = fmaxf(b0, b1);                                                        \
        tmax = fmaxf(tmax, __shfl_xor(tmax, 32));                                          \
        float fac = 1.0f;                                                                  \
        if (__any(tmax > m_run + DEFER_THR)) {                                             \
            const float m_new = fmaxf(m_run, tmax);                                        \
            fac = __builtin_amdgcn_exp2f(m_run - m_new);                                   \
            m_run = m_new;                                                                 \
            _Pragma("unroll") for (int r = 0; r < 16; ++r) { O0[r] *= fac; O1[r] *= fac; } \
        }                                                                                  \
        float tsum = 0.f;                                                                  \
        _Pragma("unroll") for (int r = 0; r < 16; ++r) {                                   \
            S[r] = __builtin_amdgcn_exp2f(S[r] - m_run);                                   \
            tsum += S[r];                                                                  \
        }                                                                                  \
        tsum += __shfl_xor(tsum, 32);                                                      \
        l_run = l_run * fac + tsum;                                                        \
        unsigned int wd[8];                                                                \
        _Pragma("unroll") for (int j = 0; j < 8; ++j) {                                    \
            const auto h2 = __builtin_amdgcn_cvt_pkrtz(S[2 * j], S[2 * j + 1]);            \
            wd[j] = __builtin_bit_cast(unsigned int, h2);                                  \
        }                                                                                  \
        xhalf(wd[0], wd[2]);                                                               \
        xhalf(wd[1], wd[3]);                                                               \
        xhalf(wd[4], wd[6]);                                                               \
        xhalf(wd[5], wd[7]);                                                               \
        H8 pf0, pf1;                                                                       \
        pf0.u[0] = wd[0]; pf0.u[1] = wd[1]; pf0.u[2] = wd[2]; pf0.u[3] = wd[3];            \
        pf1.u[0] = wd[4]; pf1.u[1] = wd[5]; pf1.u[2] = wd[6]; pf1.u[3] = wd[7];            \
        O0 = __builtin_amdgcn_mfma_f32_32x32x16_f16(                                       \
            *reinterpret_cast<const half8*>(vbase + voff[0]), pf0.h, O0, 0, 0, 0);         \
        O0 = __builtin_amdgcn_mfma_f32_32x32x16_f16(                                       \
            *reinterpret_cast<const half8*>(vbase + voff[1]), pf1.h, O0, 0, 0, 0);         \
        O1 = __builtin_amdgcn_mfma_f32_32x32x16_f16(                                       \
            *reinterpret_cast<const half8*>(vbase + voff[2]), pf0.h, O1, 0, 0, 0);         \
        O1 = __builtin_amdgcn_mfma_f32_32x32x16_f16(                                       \
            *reinterpret_cast<const half8*>(vbase + voff[3]), pf1.h, O1, 0, 0, 0);         \
    } while (0)

    auto xhalf = [&](unsigned int& a, unsigned int& cx) {
        const unsigned int y = hi ? a : cx;
        const unsigned int sy = __shfl_xor(y, 32);
        const unsigned int na = hi ? sy : a;
        const unsigned int nc = hi ? cx : sy;
        a = na; cx = nc;
    };

    for (int ih = 0; ih < 32; ++ih) {
        // ---- half A (it = 2ih): stage tiles 4ih+2,4ih+3 -> slots 2,3; compute slot p
        if (tid < 256) {
            GLOAD_LDS16(khp, smem + 2 * 4096 + c * 16);
            GLOAD_LDS16(khp + KD, smem + 3 * 4096 + c * 16);
            GLOAD_LDS16(klp, smem + 16384 + 2 * 4096 + c * 16);
            GLOAD_LDS16(klp + KD, smem + 16384 + 3 * 4096 + c * 16);
        } else {
            GLOAD_LDS16(vpp, smem + 32768 + 2 * 4096 + c * 16);
            GLOAD_LDS16(vpp + KBLK, smem + 32768 + 3 * 4096 + c * 16);
        }
        PROCESS(p);
        __syncthreads();

        // ---- half B (it = 2ih+1): stage tiles 4ih+4,4ih+5 -> slots 0,1; compute slot 2+p
        if (ih < 31) {
            if (tid < 256) {
                GLOAD_LDS16(khp + 2 * KD, smem + c * 16);
                GLOAD_LDS16(khp + 3 * KD, smem + 4096 + c * 16);
                GLOAD_LDS16(klp + 2 * KD, smem + 16384 + c * 16);
                GLOAD_LDS16(klp + 3 * KD, smem + 16384 + 4096 + c * 16);
            } else {
                GLOAD_LDS16(vpp + 2 * KBLK, smem + 32768 + c * 16);
                GLOAD_LDS16(vpp + 3 * KBLK, smem + 32768 + 4096 + c * 16);
            }
        }
        PROCESS(2 + p);
        __syncthreads();

        khp += 4 * KD;
        klp += 4 * KD;
        vpp += 4 * KBLK;
    }
#undef PROCESS

    // ---- merge k-parity pairs (wave p=1 -> LDS; wave p=0 combines, stores) ----
    float* mO = (float*)smem;                 // [qg][dblk][rr][256] : 32KB (reuses slots)
    float* ml = (float*)(smem + 32768);       // [qg][{m,l}][32] : 1KB

    if (p == 1) {
#pragma unroll
        for (int dblk = 0; dblk < 2; ++dblk)
#pragma unroll
            for (int rr = 0; rr < 4; ++rr) {
                f32x4 v;
                if (dblk == 0) {
                    v[0] = O0[rr * 4 + 0]; v[1] = O0[rr * 4 + 1];
                    v[2] = O0[rr * 4 + 2]; v[3] = O0[rr * 4 + 3];
                } else {
                    v[0] = O1[rr * 4 + 0]; v[1] = O1[rr * 4 + 1];
                    v[2] = O1[rr * 4 + 2]; v[3] = O1[rr * 4 + 3];
                }
                *reinterpret_cast<f32x4*>(mO + (((qg * 2 + dblk) * 4 + rr) << 8) + lane * 4) = v;
            }
        if (hi == 0) {
            ml[qg * 64 + l31] = m_run;
            ml[qg * 64 + 32 + l31] = l_run;
        }
    }
    __syncthreads();
    if (p == 0) {
        const float m1 = ml[qg * 64 + l31];
        const float l1 = ml[qg * 64 + 32 + l31];
        const float mm = fmaxf(m_run, m1);
        float f0 = __builtin_amdgcn_exp2f(m_run - mm);
        float f1 = __builtin_amdgcn_exp2f(m1 - mm);
        const float inv = 1.0f / (l_run * f0 + l1 * f1);
        f0 *= inv; f1 *= inv;
        float* orow = Out + ((size_t)b * Ss + q0 + qg * 32 + l31) * Dd;
#pragma unroll
        for (int dblk = 0; dblk < 2; ++dblk)
#pragma unroll
            for (int rr = 0; rr < 4; ++rr) {
                const f32x4 ov = *reinterpret_cast<const f32x4*>(
                    mO + (((qg * 2 + dblk) * 4 + rr) << 8) + lane * 4);
                f32x4 res;
#pragma unroll
                for (int j = 0; j < 4; ++j) {
                    const float mine = (dblk == 0) ? O0[rr * 4 + j] : O1[rr * 4 + j];
                    res[j] = mine * f0 + ov[j] * f1;
                }
                // d = dblk*32 + 8*rr + 4*hi + j
                *reinterpret_cast<f32x4*>(orow + dblk * 32 + rr * 8 + hi * 4) = res;
            }
    }
}

// ---------------- fallback (validated round-1 kernel) if workspace too small ---------
__global__ __launch_bounds__(256)
void attn_fwd_fallback(const float* __restrict__ Q, const float* __restrict__ K,
                       const float* __restrict__ V, const float* __restrict__ inv_scale,
                       float* __restrict__ Out)
{
    __shared__ __align__(16) ushort_t sKhi[KBLK * Dd];
    __shared__ __align__(16) ushort_t sKlo[KBLK * Dd];
    __shared__ __align__(16) ushort_t sVt[Dd * KBLK];
    __shared__ __align__(16) ushort_t sP[4][16 * KBLK];

    const int tid = threadIdx.x;
    const int lane = tid & 63;
    const int w = tid >> 6;
    const int q15 = lane & 15;
    const int g = lane >> 4;
    const int b = blockIdx.x >> 6;
    const int q0 = (blockIdx.x & 63) * 64;
    const float scale = 1.0f / inv_scale[0];

    const float* qptr = Q + (((size_t)b * Ss) + q0 + w * 16 + q15) * Dd;
    bf16x8 qhi[2], qlo[2];
#pragma unroll
    for (int ds = 0; ds < 2; ++ds) {
        const float4 f0 = *reinterpret_cast<const float4*>(qptr + ds * 32 + g * 8);
        const float4 f1 = *reinterpret_cast<const float4*>(qptr + ds * 32 + g * 8 + 4);
        float xs[8] = {f0.x, f0.y, f0.z, f0.w, f1.x, f1.y, f1.z, f1.w};
#pragma unroll
        for (int i = 0; i < 8; ++i) {
            __bf16 h = (__bf16)xs[i];
            qhi[ds][i] = h;
            qlo[ds][i] = (__bf16)(xs[i] - (float)h);
        }
    }
    const int krs = tid >> 3;
    const int kc8 = (tid & 7) * 8;
    const int kidx = krs * Dd + (kc8 ^ ((krs & 7) << 3));
    const float* kbase = K + ((size_t)b * Ss) * Dd;
    const int vd = tid & 63;
    const int vk8 = (tid >> 6) * 8;
    const int vidx = vd * KBLK + (vk8 ^ ((vd & 3) << 3));
    const float* vbase = V + ((size_t)b * Ss) * Dd;

    f32x4 Oacc[4];
#pragma unroll
    for (int dt = 0; dt < 4; ++dt)
#pragma unroll
        for (int r = 0; r < 4; ++r) Oacc[dt][r] = 0.f;
    float m_run = -INFINITY, l_run = 0.f;

    for (int k0 = 0; k0 < Ss; k0 += KBLK) {
        {
            const float* p0 = kbase + (size_t)(k0 + krs) * Dd + kc8;
            const float4 a = *reinterpret_cast<const float4*>(p0);
            const float4 c = *reinterpret_cast<const float4*>(p0 + 4);
            float xs[8] = {a.x, a.y, a.z, a.w, c.x, c.y, c.z, c.w};
            bf16x8 h8, l8;
#pragma unroll
            for (int i = 0; i < 8; ++i) {
                __bf16 h = (__bf16)xs[i];
                h8[i] = h;
                l8[i] = (__bf16)(xs[i] - (float)h);
            }
            *reinterpret_cast<bf16x8*>(&sKhi[kidx]) = h8;
            *reinterpret_cast<bf16x8*>(&sKlo[kidx]) = l8;
        }
        {
            bf16x8 v8;
#pragma unroll
            for (int j = 0; j < 8; ++j) v8[j] = (__bf16)vbase[(size_t)(k0 + vk8 + j) * Dd + vd];
            *reinterpret_cast<bf16x8*>(&sVt[vidx]) = v8;
        }
        __syncthreads();

        float z[2][4];
#pragma unroll
        for (int t = 0; t < 2; ++t) {
            const int krow = t * 16 + q15;
            f32x4 acc;
            acc[0] = acc[1] = acc[2] = acc[3] = 0.f;
#pragma unroll
            for (int ds = 0; ds < 2; ++ds) {
                const int ci = (ds * 32 + g * 8) ^ ((krow & 7) << 3);
                const bf16x8 kh = *reinterpret_cast<const bf16x8*>(&sKhi[krow * Dd + ci]);
                const bf16x8 kl = *reinterpret_cast<const bf16x8*>(&sKlo[krow * Dd + ci]);
                acc = __builtin_amdgcn_mfma_f32_16x16x32_bf16(kh, qhi[ds], acc, 0, 0, 0);
                acc = __builtin_amdgcn_mfma_f32_16x16x32_bf16(kl, qhi[ds], acc, 0, 0, 0);
                acc = __builtin_amdgcn_mfma_f32_16x16x32_bf16(kh, qlo[ds], acc, 0, 0, 0);
            }
#pragma unroll
            for (int r = 0; r < 4; ++r) z[t][r] = acc[r] * scale;
        }

        float tmax = z[0][0];
#pragma unroll
        for (int t = 0; t < 2; ++t)
#pragma unroll
            for (int r = 0; r < 4; ++r) tmax = fmaxf(tmax, z[t][r]);
        tmax = fmaxf(tmax, __shfl_xor(tmax, 16));
        tmax = fmaxf(tmax, __shfl_xor(tmax, 32));
        const float m_new = fmaxf(m_run, tmax);

        float pz[2][4];
        float tsum = 0.f;
#pragma unroll
        for (int t = 0; t < 2; ++t)
#pragma unroll
            for (int r = 0; r < 4; ++r) {
                const float e = __builtin_amdgcn_exp2f((z[t][r] - m_new) * kLOG2E);
                pz[t][r] = e;
                tsum += e;
            }
        tsum += __shfl_xor(tsum, 16);
        tsum += __shfl_xor(tsum, 32);
        const float fac = __builtin_amdgcn_exp2f((m_run - m_new) * kLOG2E);
        l_run = l_run * fac + tsum;
        m_run = m_new;

#pragma unroll
        for (int t = 0; t < 2; ++t) {
            bf16x4 pb;
#pragma unroll
            for (int r = 0; r < 4; ++r) pb[r] = (__bf16)pz[t][r];
            const int pidx = q15 * KBLK + ((t * 16 + g * 4) ^ ((q15 & 3) << 3));
            *reinterpret_cast<bf16x4*>(&sP[w][pidx]) = pb;
        }
        {
            const float fr0 = __shfl(fac, g * 4 + 0);
            const float fr1 = __shfl(fac, g * 4 + 1);
            const float fr2 = __shfl(fac, g * 4 + 2);
            const float fr3 = __shfl(fac, g * 4 + 3);
#pragma unroll
            for (int dt = 0; dt < 4; ++dt) {
                Oacc[dt][0] *= fr0; Oacc[dt][1] *= fr1;
                Oacc[dt][2] *= fr2; Oacc[dt][3] *= fr3;
            }
        }
        const int paidx = q15 * KBLK + ((g * 8) ^ ((q15 & 3) << 3));
        const bf16x8 pa = *reinterpret_cast<const bf16x8*>(&sP[w][paidx]);
#pragma unroll
        for (int dt = 0; dt < 4; ++dt) {
            const int dd = dt * 16 + q15;
            const bf16x8 vf =
                *reinterpret_cast<const bf16x8*>(&sVt[dd * KBLK + ((g * 8) ^ ((dd & 3) << 3))]);
            Oacc[dt] = __builtin_amdgcn_mfma_f32_16x16x32_bf16(pa, vf, Oacc[dt], 0, 0, 0);
        }
        __syncthreads();
    }

    const float invl = 1.0f / l_run;
    float il[4];
#pragma unroll
    for (int r = 0; r < 4; ++r) il[r] = __shfl(invl, g * 4 + r);
    float* obase = Out + (((size_t)b * Ss) + q0 + w * 16) * Dd;
#pragma unroll
    for (int dt = 0; dt < 4; ++dt)
#pragma unroll
        for (int r = 0; r < 4; ++r)
            obase[(size_t)(g * 4 + r) * Dd + dt * 16 + q15] = Oacc[dt][r] * il[r];
}

extern "C" void kernel_launch(void* const* d_in, const int* in_sizes, int n_in,
                              void* d_out, int out_size, void* d_ws, size_t ws_size,
                              hipStream_t stream)
{
    const float* q = (const float*)d_in[0];
    const float* k = (const float*)d_in[1];
    const float* v = (const float*)d_in[2];
    const float* inv_scale = (const float*)d_in[3];
    float* out = (float*)d_out;
    (void)in_sizes; (void)n_in; (void)out_size;

    const size_t NKV = (size_t)Bb * Ss * Dd;                 // elements per K/V tensor
    const size_t need = NKV * 3 * sizeof(_Float16);          // Khi + Klo + Vt

    if (ws_size >= need) {
        _Float16* Khi = (_Float16*)d_ws;
        _Float16* Klo = Khi + NKV;
        _Float16* Vt = Klo + NKV;
        hipLaunchKernelGGL(prep_f16s, dim3(KP_BLOCKS + VT_BLOCKS), dim3(256), 0, stream,
                           k, v, Khi, Klo, Vt);
        hipLaunchKernelGGL(attn_fwd_v15, dim3(Bb * (Ss / QBLK)), dim3(512), 0, stream,
                           q, inv_scale, Khi, Klo, Vt, out);
    } else {
        hipLaunchKernelGGL(attn_fwd_fallback, dim3(Bb * 64), dim3(256), 0, stream,
                           q, k, v, inv_scale, out);
    }
}

// Round 16
// 175.010 us; speedup vs baseline: 1.0154x; 1.0154x over previous
//
#include <hip/hip_runtime.h>
#include <hip/hip_bf16.h>

typedef float f32x4 __attribute__((ext_vector_type(4)));
typedef float f32x16 __attribute__((ext_vector_type(16)));
typedef _Float16 half8 __attribute__((ext_vector_type(8)));
typedef __bf16 bf16x8 __attribute__((ext_vector_type(8)));
typedef __bf16 bf16x4 __attribute__((ext_vector_type(4)));
typedef unsigned short ushort_t;

constexpr int Bb = 16, Ss = 4096, Dd = 64;
constexpr int KBLK = 32, QBLK = 128;
constexpr int NT = Ss / KBLK;   // 128
constexpr float kLOG2E = 1.44269504088896340736f;
constexpr float DEFER_THR = 10.0f;   // exp2(10)=1024 max P; fp16-safe

constexpr int KP_BLOCKS = (Bb * Ss * Dd / 8) / 256;      // 2048
constexpr int VT_BLOCKS = (Bb * Dd * (Ss / 32)) / 256;   // 512

#define GLOAD_LDS16(gp, lp)                                                              \
    __builtin_amdgcn_global_load_lds(                                                    \
        (const __attribute__((address_space(1))) void*)(gp),                             \
        (__attribute__((address_space(3))) void*)(lp), 16, 0, 0)

// ------- pre-pass: K -> f16 hi/lo [b][s][d]; V -> Vt f16 [b][d][s] (round-6 verified) -
__global__ __launch_bounds__(256)
void prep_f16s(const float* __restrict__ K, const float* __restrict__ V,
               _Float16* __restrict__ Khi, _Float16* __restrict__ Klo,
               _Float16* __restrict__ Vt)
{
    const int bid = blockIdx.x;
    if (bid < KP_BLOCKS) {
        const size_t idx = ((size_t)bid * 256 + threadIdx.x) * 8;
        const float4 a = *reinterpret_cast<const float4*>(K + idx);
        const float4 c = *reinterpret_cast<const float4*>(K + idx + 4);
        float xs[8] = {a.x, a.y, a.z, a.w, c.x, c.y, c.z, c.w};
        half8 h8, l8;
#pragma unroll
        for (int i = 0; i < 8; ++i) {
            const _Float16 h = (_Float16)xs[i];
            h8[i] = h;
            l8[i] = (_Float16)(xs[i] - (float)h);
        }
        *reinterpret_cast<half8*>(Khi + idx) = h8;
        *reinterpret_cast<half8*>(Klo + idx) = l8;
    } else {
        const int t = (bid - KP_BLOCKS) * 256 + threadIdx.x;
        const int d = t & 63;
        const int s32 = (t >> 6) & (Ss / 32 - 1);
        const int b = t >> 13;
        const float* vp = V + ((size_t)b * Ss + (size_t)s32 * 32) * Dd + d;
        __align__(16) _Float16 ob[32];
#pragma unroll
        for (int j = 0; j < 32; ++j) ob[j] = (_Float16)vp[(size_t)j * Dd];
        _Float16* op = Vt + ((size_t)b * Dd + d) * Ss + (size_t)s32 * 32;
#pragma unroll
        for (int j8 = 0; j8 < 4; ++j8)
            *reinterpret_cast<half8*>(op + j8 * 8) = *reinterpret_cast<half8*>(ob + j8 * 8);
    }
}

union H8 { half8 h; unsigned int u[4]; };

// ------- main v16: v14 (160us best) + dual-S QK chain split (ONLY change) -------------
// 8 waves (512 thr): wave w = (qg = w>>1) q-group (32 rows of 128), (p = w&1) k-parity.
// Grid 512 blocks = exactly 2 blocks/CU; 16 waves/CU = 4/SIMD. launch_bounds (512,4)
// KEPT from v14 — (512,3) in r15 dropped residency to 1 block/CU (-11%).
// QK: two independent 6-MFMA chains (Sa: ks0-1, Sb: ks2-3), interleaved issue ->
// halves the serial accumulator-dependency critical path; merged with 16 v_add_f32.
__global__ __launch_bounds__(512, 4)
void attn_fwd_v16(const float* __restrict__ Q, const float* __restrict__ inv_scale,
                  const _Float16* __restrict__ Khi, const _Float16* __restrict__ Klo,
                  const _Float16* __restrict__ Vt, float* __restrict__ Out)
{
    __shared__ __align__(16) unsigned char smem[48 * 1024];

    const int tid = threadIdx.x;
    const int lane = tid & 63;
    const int w = tid >> 6;
    const int p = w & 1;
    const int qg = w >> 1;          // 0..3
    const int l31 = lane & 31;
    const int hi = lane >> 5;

    // T1 XCD swizzle: 512 blocks -> each XCD owns 64 consecutive (2 batches)
    const int bid = (blockIdx.x & 7) * 64 + (blockIdx.x >> 3);
    const int b = bid >> 5;
    const int q0 = (bid & 31) * QBLK;

    const _Float16* KhB = Khi + (size_t)b * Ss * Dd;
    const _Float16* KlB = Klo + (size_t)b * Ss * Dd;
    const _Float16* VB = Vt + (size_t)b * Dd * Ss;

    // staging: linear LDS dest, swizzle pre-applied on the GLOBAL source (rule #21).
    // waves 0-3 stage Khi+Klo, waves 4-7 stage Vt.
    const int c = tid & 255;
    const int kk = c >> 3;
    const int ksrc = kk * Dd + (((c & 7) ^ (kk & 7)) << 3);
    const int dd_ = c >> 2;
    const size_t vsrc = (size_t)dd_ * Ss + (((c & 3) ^ ((dd_ >> 1) & 3)) << 3);

#define STAGE(t)                                                                            \
    do {                                                                                    \
        const int _sl = (t) & 3;                                                            \
        if (tid < 256) {                                                                    \
            GLOAD_LDS16(KhB + (size_t)(t) * (KBLK * Dd) + ksrc,                             \
                        smem + _sl * 4096 + c * 16);                                        \
            GLOAD_LDS16(KlB + (size_t)(t) * (KBLK * Dd) + ksrc,                             \
                        smem + 16384 + _sl * 4096 + c * 16);                                \
        } else {                                                                            \
            GLOAD_LDS16(VB + (size_t)(t) * KBLK + vsrc,                                     \
                        smem + 32768 + _sl * 4096 + c * 16);                                \
        }                                                                                   \
    } while (0)

    STAGE(0);
    STAGE(1);

    // LDS read byte-offsets (swizzled), constant per thread
    int koff[4], voff[4];
#pragma unroll
    for (int ks = 0; ks < 4; ++ks)
        koff[ks] = l31 * 128 + ((((ks << 1) + hi) ^ (l31 & 7)) << 4);
#pragma unroll
    for (int i = 0; i < 4; ++i) {   // i = dblk*2 + ks ; conflict-free V swizzle
        const int d = (i >> 1) * 32 + l31;
        voff[i] = d * 64 + (((((i & 1) << 1) + hi) ^ ((d >> 1) & 3)) << 4);
    }

    // Q fragments f16 hi/lo, scale*log2e folded; lane: col q = l31, d = ks*16 + hi*8 ..+8
    H8 qhi[4], qlo[4];
    {
        const float s2 = (1.0f / inv_scale[0]) * kLOG2E;
        const float* qrow = Q + ((size_t)b * Ss + q0 + qg * 32 + l31) * Dd;
#pragma unroll
        for (int ks = 0; ks < 4; ++ks) {
            const int d0 = ks * 16 + hi * 8;
            const float4 a = *reinterpret_cast<const float4*>(qrow + d0);
            const float4 cc = *reinterpret_cast<const float4*>(qrow + d0 + 4);
            float xs[8] = {a.x, a.y, a.z, a.w, cc.x, cc.y, cc.z, cc.w};
#pragma unroll
            for (int i = 0; i < 8; ++i) {
                const float x = xs[i] * s2;
                const _Float16 h = (_Float16)x;
                qhi[ks].h[i] = h;
                qlo[ks].h[i] = (_Float16)(x - (float)h);
            }
        }
    }

    f32x16 O0, O1;
#pragma unroll
    for (int r = 0; r < 16; ++r) { O0[r] = 0.f; O1[r] = 0.f; }
    float m_run = -INFINITY, l_run = 0.f;

    __syncthreads();   // tiles 0,1 resident (barrier drains vmcnt)

    for (int it = 0; it < NT / 2; ++it) {
        const int t = 2 * it + p;
        const unsigned char* khbase = smem + (t & 3) * 4096;
        const unsigned char* klbase = smem + 16384 + (t & 3) * 4096;
        const unsigned char* vbase = smem + 32768 + (t & 3) * 4096;

        if (it < NT / 2 - 1) { STAGE(2 * it + 2); STAGE(2 * it + 3); }

        // ---- S^T = K·Q^T: two independent 6-MFMA chains, interleaved issue ----
        const half8 kh0 = *reinterpret_cast<const half8*>(khbase + koff[0]);
        const half8 kl0 = *reinterpret_cast<const half8*>(klbase + koff[0]);
        const half8 kh1 = *reinterpret_cast<const half8*>(khbase + koff[1]);
        const half8 kl1 = *reinterpret_cast<const half8*>(klbase + koff[1]);
        const half8 kh2 = *reinterpret_cast<const half8*>(khbase + koff[2]);
        const half8 kl2 = *reinterpret_cast<const half8*>(klbase + koff[2]);
        const half8 kh3 = *reinterpret_cast<const half8*>(khbase + koff[3]);
        const half8 kl3 = *reinterpret_cast<const half8*>(klbase + koff[3]);

        f32x16 Sa, Sb;
#pragma unroll
        for (int r = 0; r < 16; ++r) { Sa[r] = 0.f; Sb[r] = 0.f; }
        Sa = __builtin_amdgcn_mfma_f32_32x32x16_f16(kh0, qhi[0].h, Sa, 0, 0, 0);
        Sb = __builtin_amdgcn_mfma_f32_32x32x16_f16(kh2, qhi[2].h, Sb, 0, 0, 0);
        Sa = __builtin_amdgcn_mfma_f32_32x32x16_f16(kl0, qhi[0].h, Sa, 0, 0, 0);
        Sb = __builtin_amdgcn_mfma_f32_32x32x16_f16(kl2, qhi[2].h, Sb, 0, 0, 0);
        Sa = __builtin_amdgcn_mfma_f32_32x32x16_f16(kh0, qlo[0].h, Sa, 0, 0, 0);
        Sb = __builtin_amdgcn_mfma_f32_32x32x16_f16(kh2, qlo[2].h, Sb, 0, 0, 0);
        Sa = __builtin_amdgcn_mfma_f32_32x32x16_f16(kh1, qhi[1].h, Sa, 0, 0, 0);
        Sb = __builtin_amdgcn_mfma_f32_32x32x16_f16(kh3, qhi[3].h, Sb, 0, 0, 0);
        Sa = __builtin_amdgcn_mfma_f32_32x32x16_f16(kl1, qhi[1].h, Sa, 0, 0, 0);
        Sb = __builtin_amdgcn_mfma_f32_32x32x16_f16(kl3, qhi[3].h, Sb, 0, 0, 0);
        Sa = __builtin_amdgcn_mfma_f32_32x32x16_f16(kh1, qlo[1].h, Sa, 0, 0, 0);
        Sb = __builtin_amdgcn_mfma_f32_32x32x16_f16(kh3, qlo[3].h, Sb, 0, 0, 0);

        f32x16 S;
#pragma unroll
        for (int r = 0; r < 16; ++r) S[r] = Sa[r] + Sb[r];
        // lane owns col q=l31; rows k = (r&3) + 8*(r>>2) + 4*hi (16 of 32; rest in lane^32)

        // ---- online softmax (log2 domain), defer-max ----
        float tmax = S[0];
#pragma unroll
        for (int r = 1; r < 16; ++r) tmax = fmaxf(tmax, S[r]);
        tmax = fmaxf(tmax, __shfl_xor(tmax, 32));

        float fac = 1.0f;
        if (__any(tmax > m_run + DEFER_THR)) {
            const float m_new = fmaxf(m_run, tmax);
            fac = __builtin_amdgcn_exp2f(m_run - m_new);
            m_run = m_new;
#pragma unroll
            for (int r = 0; r < 16; ++r) { O0[r] *= fac; O1[r] *= fac; }
        }

        float tsum = 0.f;
#pragma unroll
        for (int r = 0; r < 16; ++r) {
            S[r] = __builtin_amdgcn_exp2f(S[r] - m_run);
            tsum += S[r];
        }
        tsum += __shfl_xor(tsum, 32);
        l_run = l_run * fac + tsum;

        // ---- pack P to f16 words, cross-half exchange to form B-fragments ----
        unsigned int wd[8];
#pragma unroll
        for (int j = 0; j < 8; ++j) {
            const auto h2 = __builtin_amdgcn_cvt_pkrtz(S[2 * j], S[2 * j + 1]);
            wd[j] = __builtin_bit_cast(unsigned int, h2);
        }
        auto xhalf = [&](unsigned int& a, unsigned int& cx) {
            const unsigned int y = hi ? a : cx;
            const unsigned int sy = __shfl_xor(y, 32);
            const unsigned int na = hi ? sy : a;
            const unsigned int nc = hi ? cx : sy;
            a = na; cx = nc;
        };
        xhalf(wd[0], wd[2]);
        xhalf(wd[1], wd[3]);
        xhalf(wd[4], wd[6]);
        xhalf(wd[5], wd[7]);

        H8 pf0, pf1;
        pf0.u[0] = wd[0]; pf0.u[1] = wd[1]; pf0.u[2] = wd[2]; pf0.u[3] = wd[3];
        pf1.u[0] = wd[4]; pf1.u[1] = wd[5]; pf1.u[2] = wd[6]; pf1.u[3] = wd[7];

        // ---- O^T += V^T · P  (C: col = q = l31, row = d) ----
        O0 = __builtin_amdgcn_mfma_f32_32x32x16_f16(
            *reinterpret_cast<const half8*>(vbase + voff[0]), pf0.h, O0, 0, 0, 0);
        O0 = __builtin_amdgcn_mfma_f32_32x32x16_f16(
            *reinterpret_cast<const half8*>(vbase + voff[1]), pf1.h, O0, 0, 0, 0);
        O1 = __builtin_amdgcn_mfma_f32_32x32x16_f16(
            *reinterpret_cast<const half8*>(vbase + voff[2]), pf0.h, O1, 0, 0, 0);
        O1 = __builtin_amdgcn_mfma_f32_32x32x16_f16(
            *reinterpret_cast<const half8*>(vbase + voff[3]), pf1.h, O1, 0, 0, 0);

        __syncthreads();   // staged tiles ready; slots free for reuse
    }

    // ---- merge k-parity pairs (wave p=1 -> LDS; wave p=0 combines, stores) ----
    float* mO = (float*)smem;                 // [qg][dblk][rr][256] : 32KB (reuses slots)
    float* ml = (float*)(smem + 32768);       // [qg][{m,l}][32] : 1KB

    if (p == 1) {
#pragma unroll
        for (int dblk = 0; dblk < 2; ++dblk)
#pragma unroll
            for (int rr = 0; rr < 4; ++rr) {
                f32x4 v;
                if (dblk == 0) {
                    v[0] = O0[rr * 4 + 0]; v[1] = O0[rr * 4 + 1];
                    v[2] = O0[rr * 4 + 2]; v[3] = O0[rr * 4 + 3];
                } else {
                    v[0] = O1[rr * 4 + 0]; v[1] = O1[rr * 4 + 1];
                    v[2] = O1[rr * 4 + 2]; v[3] = O1[rr * 4 + 3];
                }
                *reinterpret_cast<f32x4*>(mO + (((qg * 2 + dblk) * 4 + rr) << 8) + lane * 4) = v;
            }
        if (hi == 0) {
            ml[qg * 64 + l31] = m_run;
            ml[qg * 64 + 32 + l31] = l_run;
        }
    }
    __syncthreads();
    if (p == 0) {
        const float m1 = ml[qg * 64 + l31];
        const float l1 = ml[qg * 64 + 32 + l31];
        const float mm = fmaxf(m_run, m1);
        float f0 = __builtin_amdgcn_exp2f(m_run - mm);
        float f1 = __builtin_amdgcn_exp2f(m1 - mm);
        const float inv = 1.0f / (l_run * f0 + l1 * f1);
        f0 *= inv; f1 *= inv;
        float* orow = Out + ((size_t)b * Ss + q0 + qg * 32 + l31) * Dd;
#pragma unroll
        for (int dblk = 0; dblk < 2; ++dblk)
#pragma unroll
            for (int rr = 0; rr < 4; ++rr) {
                const f32x4 ov = *reinterpret_cast<const f32x4*>(
                    mO + (((qg * 2 + dblk) * 4 + rr) << 8) + lane * 4);
                f32x4 res;
#pragma unroll
                for (int j = 0; j < 4; ++j) {
                    const float mine = (dblk == 0) ? O0[rr * 4 + j] : O1[rr * 4 + j];
                    res[j] = mine * f0 + ov[j] * f1;
                }
                // d = dblk*32 + 8*rr + 4*hi + j
                *reinterpret_cast<f32x4*>(orow + dblk * 32 + rr * 8 + hi * 4) = res;
            }
    }
#undef STAGE
}

// ---------------- fallback (validated round-1 kernel) if workspace too small ---------
__global__ __launch_bounds__(256)
void attn_fwd_fallback(const float* __restrict__ Q, const float* __restrict__ K,
                       const float* __restrict__ V, const float* __restrict__ inv_scale,
                       float* __restrict__ Out)
{
    __shared__ __align__(16) ushort_t sKhi[KBLK * Dd];
    __shared__ __align__(16) ushort_t sKlo[KBLK * Dd];
    __shared__ __align__(16) ushort_t sVt[Dd * KBLK];
    __shared__ __align__(16) ushort_t sP[4][16 * KBLK];

    const int tid = threadIdx.x;
    const int lane = tid & 63;
    const int w = tid >> 6;
    const int q15 = lane & 15;
    const int g = lane >> 4;
    const int b = blockIdx.x >> 6;
    const int q0 = (blockIdx.x & 63) * 64;
    const float scale = 1.0f / inv_scale[0];

    const float* qptr = Q + (((size_t)b * Ss) + q0 + w * 16 + q15) * Dd;
    bf16x8 qhi[2], qlo[2];
#pragma unroll
    for (int ds = 0; ds < 2; ++ds) {
        const float4 f0 = *reinterpret_cast<const float4*>(qptr + ds * 32 + g * 8);
        const float4 f1 = *reinterpret_cast<const float4*>(qptr + ds * 32 + g * 8 + 4);
        float xs[8] = {f0.x, f0.y, f0.z, f0.w, f1.x, f1.y, f1.z, f1.w};
#pragma unroll
        for (int i = 0; i < 8; ++i) {
            __bf16 h = (__bf16)xs[i];
            qhi[ds][i] = h;
            qlo[ds][i] = (__bf16)(xs[i] - (float)h);
        }
    }
    const int krs = tid >> 3;
    const int kc8 = (tid & 7) * 8;
    const int kidx = krs * Dd + (kc8 ^ ((krs & 7) << 3));
    const float* kbase = K + ((size_t)b * Ss) * Dd;
    const int vd = tid & 63;
    const int vk8 = (tid >> 6) * 8;
    const int vidx = vd * KBLK + (vk8 ^ ((vd & 3) << 3));
    const float* vbase = V + ((size_t)b * Ss) * Dd;

    f32x4 Oacc[4];
#pragma unroll
    for (int dt = 0; dt < 4; ++dt)
#pragma unroll
        for (int r = 0; r < 4; ++r) Oacc[dt][r] = 0.f;
    float m_run = -INFINITY, l_run = 0.f;

    for (int k0 = 0; k0 < Ss; k0 += KBLK) {
        {
            const float* p0 = kbase + (size_t)(k0 + krs) * Dd + kc8;
            const float4 a = *reinterpret_cast<const float4*>(p0);
            const float4 c = *reinterpret_cast<const float4*>(p0 + 4);
            float xs[8] = {a.x, a.y, a.z, a.w, c.x, c.y, c.z, c.w};
            bf16x8 h8, l8;
#pragma unroll
            for (int i = 0; i < 8; ++i) {
                __bf16 h = (__bf16)xs[i];
                h8[i] = h;
                l8[i] = (__bf16)(xs[i] - (float)h);
            }
            *reinterpret_cast<bf16x8*>(&sKhi[kidx]) = h8;
            *reinterpret_cast<bf16x8*>(&sKlo[kidx]) = l8;
        }
        {
            bf16x8 v8;
#pragma unroll
            for (int j = 0; j < 8; ++j) v8[j] = (__bf16)vbase[(size_t)(k0 + vk8 + j) * Dd + vd];
            *reinterpret_cast<bf16x8*>(&sVt[vidx]) = v8;
        }
        __syncthreads();

        float z[2][4];
#pragma unroll
        for (int t = 0; t < 2; ++t) {
            const int krow = t * 16 + q15;
            f32x4 acc;
            acc[0] = acc[1] = acc[2] = acc[3] = 0.f;
#pragma unroll
            for (int ds = 0; ds < 2; ++ds) {
                const int ci = (ds * 32 + g * 8) ^ ((krow & 7) << 3);
                const bf16x8 kh = *reinterpret_cast<const bf16x8*>(&sKhi[krow * Dd + ci]);
                const bf16x8 kl = *reinterpret_cast<const bf16x8*>(&sKlo[krow * Dd + ci]);
                acc = __builtin_amdgcn_mfma_f32_16x16x32_bf16(kh, qhi[ds], acc, 0, 0, 0);
                acc = __builtin_amdgcn_mfma_f32_16x16x32_bf16(kl, qhi[ds], acc, 0, 0, 0);
                acc = __builtin_amdgcn_mfma_f32_16x16x32_bf16(kh, qlo[ds], acc, 0, 0, 0);
            }
#pragma unroll
            for (int r = 0; r < 4; ++r) z[t][r] = acc[r] * scale;
        }

        float tmax = z[0][0];
#pragma unroll
        for (int t = 0; t < 2; ++t)
#pragma unroll
            for (int r = 0; r < 4; ++r) tmax = fmaxf(tmax, z[t][r]);
        tmax = fmaxf(tmax, __shfl_xor(tmax, 16));
        tmax = fmaxf(tmax, __shfl_xor(tmax, 32));
        const float m_new = fmaxf(m_run, tmax);

        float pz[2][4];
        float tsum = 0.f;
#pragma unroll
        for (int t = 0; t < 2; ++t)
#pragma unroll
            for (int r = 0; r < 4; ++r) {
                const float e = __builtin_amdgcn_exp2f((z[t][r] - m_new) * kLOG2E);
                pz[t][r] = e;
                tsum += e;
            }
        tsum += __shfl_xor(tsum, 16);
        tsum += __shfl_xor(tsum, 32);
        const float fac = __builtin_amdgcn_exp2f((m_run - m_new) * kLOG2E);
        l_run = l_run * fac + tsum;
        m_run = m_new;

#pragma unroll
        for (int t = 0; t < 2; ++t) {
            bf16x4 pb;
#pragma unroll
            for (int r = 0; r < 4; ++r) pb[r] = (__bf16)pz[t][r];
            const int pidx = q15 * KBLK + ((t * 16 + g * 4) ^ ((q15 & 3) << 3));
            *reinterpret_cast<bf16x4*>(&sP[w][pidx]) = pb;
        }
        {
            const float fr0 = __shfl(fac, g * 4 + 0);
            const float fr1 = __shfl(fac, g * 4 + 1);
            const float fr2 = __shfl(fac, g * 4 + 2);
            const float fr3 = __shfl(fac, g * 4 + 3);
#pragma unroll
            for (int dt = 0; dt < 4; ++dt) {
                Oacc[dt][0] *= fr0; Oacc[dt][1] *= fr1;
                Oacc[dt][2] *= fr2; Oacc[dt][3] *= fr3;
            }
        }
        const int paidx = q15 * KBLK + ((g * 8) ^ ((q15 & 3) << 3));
        const bf16x8 pa = *reinterpret_cast<const bf16x8*>(&sP[w][paidx]);
#pragma unroll
        for (int dt = 0; dt < 4; ++dt) {
            const int dd = dt * 16 + q15;
            const bf16x8 vf =
                *reinterpret_cast<const bf16x8*>(&sVt[dd * KBLK + ((g * 8) ^ ((dd & 3) << 3))]);
            Oacc[dt] = __builtin_amdgcn_mfma_f32_16x16x32_bf16(pa, vf, Oacc[dt], 0, 0, 0);
        }
        __syncthreads();
    }

    const float invl = 1.0f / l_run;
    float il[4];
#pragma unroll
    for (int r = 0; r < 4; ++r) il[r] = __shfl(invl, g * 4 + r);
    float* obase = Out + (((size_t)b * Ss) + q0 + w * 16) * Dd;
#pragma unroll
    for (int dt = 0; dt < 4; ++dt)
#pragma unroll
        for (int r = 0; r < 4; ++r)
            obase[(size_t)(g * 4 + r) * Dd + dt * 16 + q15] = Oacc[dt][r] * il[r];
}

extern "C" void kernel_launch(void* const* d_in, const int* in_sizes, int n_in,
                              void* d_out, int out_size, void* d_ws, size_t ws_size,
                              hipStream_t stream)
{
    const float* q = (const float*)d_in[0];
    const float* k = (const float*)d_in[1];
    const float* v = (const float*)d_in[2];
    const float* inv_scale = (const float*)d_in[3];
    float* out = (float*)d_out;
    (void)in_sizes; (void)n_in; (void)out_size;

    const size_t NKV = (size_t)Bb * Ss * Dd;                 // elements per K/V tensor
    const size_t need = NKV * 3 * sizeof(_Float16);          // Khi + Klo + Vt

    if (ws_size >= need) {
        _Float16* Khi = (_Float16*)d_ws;
        _Float16* Klo = Khi + NKV;
        _Float16* Vt = Klo + NKV;
        hipLaunchKernelGGL(prep_f16s, dim3(KP_BLOCKS + VT_BLOCKS), dim3(256), 0, stream,
                           k, v, Khi, Klo, Vt);
        hipLaunchKernelGGL(attn_fwd_v16, dim3(Bb * (Ss / QBLK)), dim3(512), 0, stream,
                           q, inv_scale, Khi, Klo, Vt, out);
    } else {
        hipLaunchKernelGGL(attn_fwd_fallback, dim3(Bb * 64), dim3(256), 0, stream,
                           q, k, v, inv_scale, out);
    }
}

// Round 17
// 169.106 us; speedup vs baseline: 1.0509x; 1.0349x over previous
//
#include <hip/hip_runtime.h>
#include <hip/hip_bf16.h>

typedef float f32x4 __attribute__((ext_vector_type(4)));
typedef float f32x16 __attribute__((ext_vector_type(16)));
typedef _Float16 half8 __attribute__((ext_vector_type(8)));
typedef __bf16 bf16x8 __attribute__((ext_vector_type(8)));
typedef __bf16 bf16x4 __attribute__((ext_vector_type(4)));
typedef unsigned short ushort_t;

constexpr int Bb = 16, Ss = 4096, Dd = 64;
constexpr int KBLK = 32, QBLK = 128;
constexpr int NT = Ss / KBLK;   // 128
constexpr float kLOG2E = 1.44269504088896340736f;
constexpr float DEFER_THR = 10.0f;   // exp2(10)=1024 max P; fp16-safe

constexpr int KP_BLOCKS = (Bb * Ss * Dd / 8) / 256;      // 2048
constexpr int VT_BLOCKS = (Bb * Dd * (Ss / 32)) / 256;   // 512

#define GLOAD_LDS16(gp, lp)                                                              \
    __builtin_amdgcn_global_load_lds(                                                    \
        (const __attribute__((address_space(1))) void*)(gp),                             \
        (__attribute__((address_space(3))) void*)(lp), 16, 0, 0)

// ------- pre-pass: K -> f16 hi/lo [b][s][d]; V -> Vt f16 [b][d][s] (round-6 verified) -
__global__ __launch_bounds__(256)
void prep_f16s(const float* __restrict__ K, const float* __restrict__ V,
               _Float16* __restrict__ Khi, _Float16* __restrict__ Klo,
               _Float16* __restrict__ Vt)
{
    const int bid = blockIdx.x;
    if (bid < KP_BLOCKS) {
        const size_t idx = ((size_t)bid * 256 + threadIdx.x) * 8;
        const float4 a = *reinterpret_cast<const float4*>(K + idx);
        const float4 c = *reinterpret_cast<const float4*>(K + idx + 4);
        float xs[8] = {a.x, a.y, a.z, a.w, c.x, c.y, c.z, c.w};
        half8 h8, l8;
#pragma unroll
        for (int i = 0; i < 8; ++i) {
            const _Float16 h = (_Float16)xs[i];
            h8[i] = h;
            l8[i] = (_Float16)(xs[i] - (float)h);
        }
        *reinterpret_cast<half8*>(Khi + idx) = h8;
        *reinterpret_cast<half8*>(Klo + idx) = l8;
    } else {
        const int t = (bid - KP_BLOCKS) * 256 + threadIdx.x;
        const int d = t & 63;
        const int s32 = (t >> 6) & (Ss / 32 - 1);
        const int b = t >> 13;
        const float* vp = V + ((size_t)b * Ss + (size_t)s32 * 32) * Dd + d;
        __align__(16) _Float16 ob[32];
#pragma unroll
        for (int j = 0; j < 32; ++j) ob[j] = (_Float16)vp[(size_t)j * Dd];
        _Float16* op = Vt + ((size_t)b * Dd + d) * Ss + (size_t)s32 * 32;
#pragma unroll
        for (int j8 = 0; j8 < 4; ++j8)
            *reinterpret_cast<half8*>(op + j8 * 8) = *reinterpret_cast<half8*>(ob + j8 * 8);
    }
}

union H8 { half8 h; unsigned int u[4]; };

// ------- main v17 == v14 (verified best, 160us): v5 + conflict-free V swizzle ---------
// 8 waves (512 thr): wave w = (qg = w>>1) q-group (32 rows of 128), (p = w&1) k-parity.
// Grid 512 blocks = exactly 2 blocks/CU; 16 waves/CU = 4/SIMD. launch_bounds (512,4):
// keeps VGPR=64 arch + 2-block residency (r15: (512,3) drops to 1 block/CU, -11%).
// 3-pass split-fp16 QK (numerics floor, r8); single 12-MFMA chain (r16: split is worse).
__global__ __launch_bounds__(512, 4)
void attn_fwd_v17(const float* __restrict__ Q, const float* __restrict__ inv_scale,
                  const _Float16* __restrict__ Khi, const _Float16* __restrict__ Klo,
                  const _Float16* __restrict__ Vt, float* __restrict__ Out)
{
    __shared__ __align__(16) unsigned char smem[48 * 1024];

    const int tid = threadIdx.x;
    const int lane = tid & 63;
    const int w = tid >> 6;
    const int p = w & 1;
    const int qg = w >> 1;          // 0..3
    const int l31 = lane & 31;
    const int hi = lane >> 5;

    // T1 XCD swizzle: 512 blocks -> each XCD owns 64 consecutive (2 batches)
    const int bid = (blockIdx.x & 7) * 64 + (blockIdx.x >> 3);
    const int b = bid >> 5;
    const int q0 = (bid & 31) * QBLK;

    const _Float16* KhB = Khi + (size_t)b * Ss * Dd;
    const _Float16* KlB = Klo + (size_t)b * Ss * Dd;
    const _Float16* VB = Vt + (size_t)b * Dd * Ss;

    // staging: linear LDS dest, swizzle pre-applied on the GLOBAL source (rule #21).
    // waves 0-3 stage Khi+Klo, waves 4-7 stage Vt.
    const int c = tid & 255;
    const int kk = c >> 3;
    const int ksrc = kk * Dd + (((c & 7) ^ (kk & 7)) << 3);
    const int dd_ = c >> 2;
    const size_t vsrc = (size_t)dd_ * Ss + (((c & 3) ^ ((dd_ >> 1) & 3)) << 3);

#define STAGE(t)                                                                            \
    do {                                                                                    \
        const int _sl = (t) & 3;                                                            \
        if (tid < 256) {                                                                    \
            GLOAD_LDS16(KhB + (size_t)(t) * (KBLK * Dd) + ksrc,                             \
                        smem + _sl * 4096 + c * 16);                                        \
            GLOAD_LDS16(KlB + (size_t)(t) * (KBLK * Dd) + ksrc,                             \
                        smem + 16384 + _sl * 4096 + c * 16);                                \
        } else {                                                                            \
            GLOAD_LDS16(VB + (size_t)(t) * KBLK + vsrc,                                     \
                        smem + 32768 + _sl * 4096 + c * 16);                                \
        }                                                                                   \
    } while (0)

    STAGE(0);
    STAGE(1);

    // LDS read byte-offsets (swizzled), constant per thread
    int koff[4], voff[4];
#pragma unroll
    for (int ks = 0; ks < 4; ++ks)
        koff[ks] = l31 * 128 + ((((ks << 1) + hi) ^ (l31 & 7)) << 4);
#pragma unroll
    for (int i = 0; i < 4; ++i) {   // i = dblk*2 + ks ; conflict-free V swizzle
        const int d = (i >> 1) * 32 + l31;
        voff[i] = d * 64 + (((((i & 1) << 1) + hi) ^ ((d >> 1) & 3)) << 4);
    }

    // Q fragments f16 hi/lo, scale*log2e folded; lane: col q = l31, d = ks*16 + hi*8 ..+8
    H8 qhi[4], qlo[4];
    {
        const float s2 = (1.0f / inv_scale[0]) * kLOG2E;
        const float* qrow = Q + ((size_t)b * Ss + q0 + qg * 32 + l31) * Dd;
#pragma unroll
        for (int ks = 0; ks < 4; ++ks) {
            const int d0 = ks * 16 + hi * 8;
            const float4 a = *reinterpret_cast<const float4*>(qrow + d0);
            const float4 cc = *reinterpret_cast<const float4*>(qrow + d0 + 4);
            float xs[8] = {a.x, a.y, a.z, a.w, cc.x, cc.y, cc.z, cc.w};
#pragma unroll
            for (int i = 0; i < 8; ++i) {
                const float x = xs[i] * s2;
                const _Float16 h = (_Float16)x;
                qhi[ks].h[i] = h;
                qlo[ks].h[i] = (_Float16)(x - (float)h);
            }
        }
    }

    f32x16 O0, O1;
#pragma unroll
    for (int r = 0; r < 16; ++r) { O0[r] = 0.f; O1[r] = 0.f; }
    float m_run = -INFINITY, l_run = 0.f;

    __syncthreads();   // tiles 0,1 resident (barrier drains vmcnt)

    for (int it = 0; it < NT / 2; ++it) {
        const int t = 2 * it + p;
        const unsigned char* khbase = smem + (t & 3) * 4096;
        const unsigned char* klbase = smem + 16384 + (t & 3) * 4096;
        const unsigned char* vbase = smem + 32768 + (t & 3) * 4096;

        if (it < NT / 2 - 1) { STAGE(2 * it + 2); STAGE(2 * it + 3); }

        // ---- S^T = K·Q^T (32k x 32q), split-precision fp16 (hi*hi + lo*hi + hi*lo) ----
        f32x16 S;
#pragma unroll
        for (int r = 0; r < 16; ++r) S[r] = 0.f;
#pragma unroll
        for (int ks = 0; ks < 4; ++ks) {
            const half8 kh = *reinterpret_cast<const half8*>(khbase + koff[ks]);
            const half8 kl = *reinterpret_cast<const half8*>(klbase + koff[ks]);
            S = __builtin_amdgcn_mfma_f32_32x32x16_f16(kh, qhi[ks].h, S, 0, 0, 0);
            S = __builtin_amdgcn_mfma_f32_32x32x16_f16(kl, qhi[ks].h, S, 0, 0, 0);
            S = __builtin_amdgcn_mfma_f32_32x32x16_f16(kh, qlo[ks].h, S, 0, 0, 0);
        }
        // lane owns col q=l31; rows k = (r&3) + 8*(r>>2) + 4*hi (16 of 32; rest in lane^32)

        // ---- online softmax (log2 domain), defer-max ----
        float tmax = S[0];
#pragma unroll
        for (int r = 1; r < 16; ++r) tmax = fmaxf(tmax, S[r]);
        tmax = fmaxf(tmax, __shfl_xor(tmax, 32));

        float fac = 1.0f;
        if (__any(tmax > m_run + DEFER_THR)) {
            const float m_new = fmaxf(m_run, tmax);
            fac = __builtin_amdgcn_exp2f(m_run - m_new);
            m_run = m_new;
#pragma unroll
            for (int r = 0; r < 16; ++r) { O0[r] *= fac; O1[r] *= fac; }
        }

        float tsum = 0.f;
#pragma unroll
        for (int r = 0; r < 16; ++r) {
            S[r] = __builtin_amdgcn_exp2f(S[r] - m_run);
            tsum += S[r];
        }
        tsum += __shfl_xor(tsum, 32);
        l_run = l_run * fac + tsum;

        // ---- pack P to f16 words, cross-half exchange to form B-fragments ----
        unsigned int wd[8];
#pragma unroll
        for (int j = 0; j < 8; ++j) {
            const auto h2 = __builtin_amdgcn_cvt_pkrtz(S[2 * j], S[2 * j + 1]);
            wd[j] = __builtin_bit_cast(unsigned int, h2);
        }
        auto xhalf = [&](unsigned int& a, unsigned int& cx) {
            const unsigned int y = hi ? a : cx;
            const unsigned int sy = __shfl_xor(y, 32);
            const unsigned int na = hi ? sy : a;
            const unsigned int nc = hi ? cx : sy;
            a = na; cx = nc;
        };
        xhalf(wd[0], wd[2]);
        xhalf(wd[1], wd[3]);
        xhalf(wd[4], wd[6]);
        xhalf(wd[5], wd[7]);

        H8 pf0, pf1;
        pf0.u[0] = wd[0]; pf0.u[1] = wd[1]; pf0.u[2] = wd[2]; pf0.u[3] = wd[3];
        pf1.u[0] = wd[4]; pf1.u[1] = wd[5]; pf1.u[2] = wd[6]; pf1.u[3] = wd[7];

        // ---- O^T += V^T · P  (C: col = q = l31, row = d) ----
        O0 = __builtin_amdgcn_mfma_f32_32x32x16_f16(
            *reinterpret_cast<const half8*>(vbase + voff[0]), pf0.h, O0, 0, 0, 0);
        O0 = __builtin_amdgcn_mfma_f32_32x32x16_f16(
            *reinterpret_cast<const half8*>(vbase + voff[1]), pf1.h, O0, 0, 0, 0);
        O1 = __builtin_amdgcn_mfma_f32_32x32x16_f16(
            *reinterpret_cast<const half8*>(vbase + voff[2]), pf0.h, O1, 0, 0, 0);
        O1 = __builtin_amdgcn_mfma_f32_32x32x16_f16(
            *reinterpret_cast<const half8*>(vbase + voff[3]), pf1.h, O1, 0, 0, 0);

        __syncthreads();   // staged tiles ready; slots free for reuse
    }

    // ---- merge k-parity pairs (wave p=1 -> LDS; wave p=0 combines, stores) ----
    float* mO = (float*)smem;                 // [qg][dblk][rr][256] : 32KB (reuses slots)
    float* ml = (float*)(smem + 32768);       // [qg][{m,l}][32] : 1KB

    if (p == 1) {
#pragma unroll
        for (int dblk = 0; dblk < 2; ++dblk)
#pragma unroll
            for (int rr = 0; rr < 4; ++rr) {
                f32x4 v;
                if (dblk == 0) {
                    v[0] = O0[rr * 4 + 0]; v[1] = O0[rr * 4 + 1];
                    v[2] = O0[rr * 4 + 2]; v[3] = O0[rr * 4 + 3];
                } else {
                    v[0] = O1[rr * 4 + 0]; v[1] = O1[rr * 4 + 1];
                    v[2] = O1[rr * 4 + 2]; v[3] = O1[rr * 4 + 3];
                }
                *reinterpret_cast<f32x4*>(mO + (((qg * 2 + dblk) * 4 + rr) << 8) + lane * 4) = v;
            }
        if (hi == 0) {
            ml[qg * 64 + l31] = m_run;
            ml[qg * 64 + 32 + l31] = l_run;
        }
    }
    __syncthreads();
    if (p == 0) {
        const float m1 = ml[qg * 64 + l31];
        const float l1 = ml[qg * 64 + 32 + l31];
        const float mm = fmaxf(m_run, m1);
        float f0 = __builtin_amdgcn_exp2f(m_run - mm);
        float f1 = __builtin_amdgcn_exp2f(m1 - mm);
        const float inv = 1.0f / (l_run * f0 + l1 * f1);
        f0 *= inv; f1 *= inv;
        float* orow = Out + ((size_t)b * Ss + q0 + qg * 32 + l31) * Dd;
#pragma unroll
        for (int dblk = 0; dblk < 2; ++dblk)
#pragma unroll
            for (int rr = 0; rr < 4; ++rr) {
                const f32x4 ov = *reinterpret_cast<const f32x4*>(
                    mO + (((qg * 2 + dblk) * 4 + rr) << 8) + lane * 4);
                f32x4 res;
#pragma unroll
                for (int j = 0; j < 4; ++j) {
                    const float mine = (dblk == 0) ? O0[rr * 4 + j] : O1[rr * 4 + j];
                    res[j] = mine * f0 + ov[j] * f1;
                }
                // d = dblk*32 + 8*rr + 4*hi + j
                *reinterpret_cast<f32x4*>(orow + dblk * 32 + rr * 8 + hi * 4) = res;
            }
    }
#undef STAGE
}

// ---------------- fallback (validated round-1 kernel) if workspace too small ---------
__global__ __launch_bounds__(256)
void attn_fwd_fallback(const float* __restrict__ Q, const float* __restrict__ K,
                       const float* __restrict__ V, const float* __restrict__ inv_scale,
                       float* __restrict__ Out)
{
    __shared__ __align__(16) ushort_t sKhi[KBLK * Dd];
    __shared__ __align__(16) ushort_t sKlo[KBLK * Dd];
    __shared__ __align__(16) ushort_t sVt[Dd * KBLK];
    __shared__ __align__(16) ushort_t sP[4][16 * KBLK];

    const int tid = threadIdx.x;
    const int lane = tid & 63;
    const int w = tid >> 6;
    const int q15 = lane & 15;
    const int g = lane >> 4;
    const int b = blockIdx.x >> 6;
    const int q0 = (blockIdx.x & 63) * 64;
    const float scale = 1.0f / inv_scale[0];

    const float* qptr = Q + (((size_t)b * Ss) + q0 + w * 16 + q15) * Dd;
    bf16x8 qhi[2], qlo[2];
#pragma unroll
    for (int ds = 0; ds < 2; ++ds) {
        const float4 f0 = *reinterpret_cast<const float4*>(qptr + ds * 32 + g * 8);
        const float4 f1 = *reinterpret_cast<const float4*>(qptr + ds * 32 + g * 8 + 4);
        float xs[8] = {f0.x, f0.y, f0.z, f0.w, f1.x, f1.y, f1.z, f1.w};
#pragma unroll
        for (int i = 0; i < 8; ++i) {
            __bf16 h = (__bf16)xs[i];
            qhi[ds][i] = h;
            qlo[ds][i] = (__bf16)(xs[i] - (float)h);
        }
    }
    const int krs = tid >> 3;
    const int kc8 = (tid & 7) * 8;
    const int kidx = krs * Dd + (kc8 ^ ((krs & 7) << 3));
    const float* kbase = K + ((size_t)b * Ss) * Dd;
    const int vd = tid & 63;
    const int vk8 = (tid >> 6) * 8;
    const int vidx = vd * KBLK + (vk8 ^ ((vd & 3) << 3));
    const float* vbase = V + ((size_t)b * Ss) * Dd;

    f32x4 Oacc[4];
#pragma unroll
    for (int dt = 0; dt < 4; ++dt)
#pragma unroll
        for (int r = 0; r < 4; ++r) Oacc[dt][r] = 0.f;
    float m_run = -INFINITY, l_run = 0.f;

    for (int k0 = 0; k0 < Ss; k0 += KBLK) {
        {
            const float* p0 = kbase + (size_t)(k0 + krs) * Dd + kc8;
            const float4 a = *reinterpret_cast<const float4*>(p0);
            const float4 c = *reinterpret_cast<const float4*>(p0 + 4);
            float xs[8] = {a.x, a.y, a.z, a.w, c.x, c.y, c.z, c.w};
            bf16x8 h8, l8;
#pragma unroll
            for (int i = 0; i < 8; ++i) {
                __bf16 h = (__bf16)xs[i];
                h8[i] = h;
                l8[i] = (__bf16)(xs[i] - (float)h);
            }
            *reinterpret_cast<bf16x8*>(&sKhi[kidx]) = h8;
            *reinterpret_cast<bf16x8*>(&sKlo[kidx]) = l8;
        }
        {
            bf16x8 v8;
#pragma unroll
            for (int j = 0; j < 8; ++j) v8[j] = (__bf16)vbase[(size_t)(k0 + vk8 + j) * Dd + vd];
            *reinterpret_cast<bf16x8*>(&sVt[vidx]) = v8;
        }
        __syncthreads();

        float z[2][4];
#pragma unroll
        for (int t = 0; t < 2; ++t) {
            const int krow = t * 16 + q15;
            f32x4 acc;
            acc[0] = acc[1] = acc[2] = acc[3] = 0.f;
#pragma unroll
            for (int ds = 0; ds < 2; ++ds) {
                const int ci = (ds * 32 + g * 8) ^ ((krow & 7) << 3);
                const bf16x8 kh = *reinterpret_cast<const bf16x8*>(&sKhi[krow * Dd + ci]);
                const bf16x8 kl = *reinterpret_cast<const bf16x8*>(&sKlo[krow * Dd + ci]);
                acc = __builtin_amdgcn_mfma_f32_16x16x32_bf16(kh, qhi[ds], acc, 0, 0, 0);
                acc = __builtin_amdgcn_mfma_f32_16x16x32_bf16(kl, qhi[ds], acc, 0, 0, 0);
                acc = __builtin_amdgcn_mfma_f32_16x16x32_bf16(kh, qlo[ds], acc, 0, 0, 0);
            }
#pragma unroll
            for (int r = 0; r < 4; ++r) z[t][r] = acc[r] * scale;
        }

        float tmax = z[0][0];
#pragma unroll
        for (int t = 0; t < 2; ++t)
#pragma unroll
            for (int r = 0; r < 4; ++r) tmax = fmaxf(tmax, z[t][r]);
        tmax = fmaxf(tmax, __shfl_xor(tmax, 16));
        tmax = fmaxf(tmax, __shfl_xor(tmax, 32));
        const float m_new = fmaxf(m_run, tmax);

        float pz[2][4];
        float tsum = 0.f;
#pragma unroll
        for (int t = 0; t < 2; ++t)
#pragma unroll
            for (int r = 0; r < 4; ++r) {
                const float e = __builtin_amdgcn_exp2f((z[t][r] - m_new) * kLOG2E);
                pz[t][r] = e;
                tsum += e;
            }
        tsum += __shfl_xor(tsum, 16);
        tsum += __shfl_xor(tsum, 32);
        const float fac = __builtin_amdgcn_exp2f((m_run - m_new) * kLOG2E);
        l_run = l_run * fac + tsum;
        m_run = m_new;

#pragma unroll
        for (int t = 0; t < 2; ++t) {
            bf16x4 pb;
#pragma unroll
            for (int r = 0; r < 4; ++r) pb[r] = (__bf16)pz[t][r];
            const int pidx = q15 * KBLK + ((t * 16 + g * 4) ^ ((q15 & 3) << 3));
            *reinterpret_cast<bf16x4*>(&sP[w][pidx]) = pb;
        }
        {
            const float fr0 = __shfl(fac, g * 4 + 0);
            const float fr1 = __shfl(fac, g * 4 + 1);
            const float fr2 = __shfl(fac, g * 4 + 2);
            const float fr3 = __shfl(fac, g * 4 + 3);
#pragma unroll
            for (int dt = 0; dt < 4; ++dt) {
                Oacc[dt][0] *= fr0; Oacc[dt][1] *= fr1;
                Oacc[dt][2] *= fr2; Oacc[dt][3] *= fr3;
            }
        }
        const int paidx = q15 * KBLK + ((g * 8) ^ ((q15 & 3) << 3));
        const bf16x8 pa = *reinterpret_cast<const bf16x8*>(&sP[w][paidx]);
#pragma unroll
        for (int dt = 0; dt < 4; ++dt) {
            const int dd = dt * 16 + q15;
            const bf16x8 vf =
                *reinterpret_cast<const bf16x8*>(&sVt[dd * KBLK + ((g * 8) ^ ((dd & 3) << 3))]);
            Oacc[dt] = __builtin_amdgcn_mfma_f32_16x16x32_bf16(pa, vf, Oacc[dt], 0, 0, 0);
        }
        __syncthreads();
    }

    const float invl = 1.0f / l_run;
    float il[4];
#pragma unroll
    for (int r = 0; r < 4; ++r) il[r] = __shfl(invl, g * 4 + r);
    float* obase = Out + (((size_t)b * Ss) + q0 + w * 16) * Dd;
#pragma unroll
    for (int dt = 0; dt < 4; ++dt)
#pragma unroll
        for (int r = 0; r < 4; ++r)
            obase[(size_t)(g * 4 + r) * Dd + dt * 16 + q15] = Oacc[dt][r] * il[r];
}

extern "C" void kernel_launch(void* const* d_in, const int* in_sizes, int n_in,
                              void* d_out, int out_size, void* d_ws, size_t ws_size,
                              hipStream_t stream)
{
    const float* q = (const float*)d_in[0];
    const float* k = (const float*)d_in[1];
    const float* v = (const float*)d_in[2];
    const float* inv_scale = (const float*)d_in[3];
    float* out = (float*)d_out;
    (void)in_sizes; (void)n_in; (void)out_size;

    const size_t NKV = (size_t)Bb * Ss * Dd;                 // elements per K/V tensor
    const size_t need = NKV * 3 * sizeof(_Float16);          // Khi + Klo + Vt

    if (ws_size >= need) {
        _Float16* Khi = (_Float16*)d_ws;
        _Float16* Klo = Khi + NKV;
        _Float16* Vt = Klo + NKV;
        hipLaunchKernelGGL(prep_f16s, dim3(KP_BLOCKS + VT_BLOCKS), dim3(256), 0, stream,
                           k, v, Khi, Klo, Vt);
        hipLaunchKernelGGL(attn_fwd_v17, dim3(Bb * (Ss / QBLK)), dim3(512), 0, stream,
                           q, inv_scale, Khi, Klo, Vt, out);
    } else {
        hipLaunchKernelGGL(attn_fwd_fallback, dim3(Bb * 64), dim3(256), 0, stream,
                           q, k, v, inv_scale, out);
    }
}